// Round 2
// baseline (161.335 us; speedup 1.0000x reference)
//
#include <hip/hip_runtime.h>
#include <math.h>

// Problem constants (fixed by reference): B=32, T=2048, D=128
constexpr int B = 32;
constexpr int T = 2048;
constexpr int D = 128;

// Single kernel, no workspace.
// Thread = (b, chunk of 4 timesteps, 4 consecutive d). All bulk traffic is
// float4/int4: lanes 0..31 of a wave cover d=0..127 contiguously (512B
// segments per half-wave). Carry lookup reads a +/-16-timestep mask window
// directly from global (int4 across the 4 owned d-chains); the re-read is
// absorbed by L2/L3 (round-0 evidence: 3x mask re-read cost zero extra HBM
// fetch). Fallback serial scan only if a whole 16-step window is unobserved
// (P = 2^-16 per window).
__global__ __launch_bounds__(256)
void interp_wide_kernel(const float* __restrict__ values,
                        const float* __restrict__ times,
                        const int*   __restrict__ mask,
                        float*       __restrict__ out)
{
    const int gid = blockIdx.x * 256 + threadIdx.x;
    const int d4 = gid & 31;                 // lanes: consecutive d4 -> coalesced
    const int c  = (gid >> 5) & 511;         // chunk index over T/4 = 512
    const int b  = gid >> 14;                // 32*512 = 2^14 threads per b
    const int d0 = d4 << 2;
    const int t0 = c << 2;

    const size_t bbase = (size_t)b * T * D;
    const float* vrow = values + bbase + (size_t)t0 * D + d0;
    const float* trow = times  + bbase + (size_t)t0 * D + d0;
    const int*   mrow = mask   + bbase + (size_t)t0 * D + d0;

    // ---- phase 1: own tile, all independent wide loads ----
    float vv[4][4], tt[4][4];                // [timestep][chain]
    unsigned mb[4] = {0u, 0u, 0u, 0u};       // 4-bit own-mask per chain
#pragma unroll
    for (int i = 0; i < 4; ++i) {
        const float4 a = *reinterpret_cast<const float4*>(vrow + i * D);
        const float4 s = *reinterpret_cast<const float4*>(trow + i * D);
        const int4   m = *reinterpret_cast<const int4*>(mrow + i * D);
        vv[i][0] = a.x; vv[i][1] = a.y; vv[i][2] = a.z; vv[i][3] = a.w;
        tt[i][0] = s.x; tt[i][1] = s.y; tt[i][2] = s.z; tt[i][3] = s.w;
        mb[0] |= (m.x != 0 ? 1u : 0u) << i;
        mb[1] |= (m.y != 0 ? 1u : 0u) << i;
        mb[2] |= (m.z != 0 ? 1u : 0u) << i;
        mb[3] |= (m.w != 0 ? 1u : 0u) << i;
    }

    // ---- phase 2: mask windows (16 steps back, 16 steps forward) ----
    // fw bit k = observed at step (t0-16+k); bw bit k = observed at (t0+4+k).
    unsigned fw[4] = {0u, 0u, 0u, 0u};
    unsigned bw[4] = {0u, 0u, 0u, 0u};
#pragma unroll
    for (int k = 0; k < 16; ++k) {
        const int st = t0 - 16 + k;
        if (st >= 0) {                       // near-uniform predicate per wave
            const int4 m = *reinterpret_cast<const int4*>(
                mask + bbase + (size_t)st * D + d0);
            fw[0] |= (m.x != 0 ? 1u : 0u) << k;
            fw[1] |= (m.y != 0 ? 1u : 0u) << k;
            fw[2] |= (m.z != 0 ? 1u : 0u) << k;
            fw[3] |= (m.w != 0 ? 1u : 0u) << k;
        }
    }
#pragma unroll
    for (int k = 0; k < 16; ++k) {
        const int st = t0 + 4 + k;
        if (st < T) {
            const int4 m = *reinterpret_cast<const int4*>(
                mask + bbase + (size_t)st * D + d0);
            bw[0] |= (m.x != 0 ? 1u : 0u) << k;
            bw[1] |= (m.y != 0 ? 1u : 0u) << k;
            bw[2] |= (m.z != 0 ? 1u : 0u) << k;
            bw[3] |= (m.w != 0 ? 1u : 0u) << k;
        }
    }

    // ---- phase 3: carry indices (register bit-scan; rare fallback scans) ----
    int fi[4], bi[4];
#pragma unroll
    for (int j = 0; j < 4; ++j) {
        fi[j] = fw[j] ? (t0 - 16 + (31 - __builtin_clz(fw[j]))) : -1;
        bi[j] = bw[j] ? (t0 + 4 + __builtin_ctz(bw[j])) : -1;
    }
#pragma unroll
    for (int j = 0; j < 4; ++j) {
        if (fi[j] < 0 && t0 > 16) {          // window didn't reach t=0: scan rest
            for (int st = t0 - 17; st >= 0; --st) {
                if (mask[bbase + (size_t)st * D + d0 + j] != 0) { fi[j] = st; break; }
            }
        }
        if (bi[j] < 0 && t0 + 20 < T) {      // window didn't reach t=T-1: scan rest
            for (int st = t0 + 20; st < T; ++st) {
                if (mask[bbase + (size_t)st * D + d0 + j] != 0) { bi[j] = st; break; }
            }
        }
    }

    // ---- phase 4: batched dependent carry fetches (independent of each other) ----
    float fx[4], ft[4], bx[4], bt[4];
#pragma unroll
    for (int j = 0; j < 4; ++j) {
        const int sF = fi[j] < 0 ? 0 : fi[j];
        const int sB = bi[j] < 0 ? 0 : bi[j];
        const size_t oF = bbase + (size_t)sF * D + d0 + j;
        const size_t oB = bbase + (size_t)sB * D + d0 + j;
        fx[j] = values[oF]; ft[j] = times[oF];
        bx[j] = values[oB]; bt[j] = times[oB];
    }
    // reference init values for "no observation on that side"
    const float4 tf4 = *reinterpret_cast<const float4*>(times + bbase + d0);
    const float4 tl4 = *reinterpret_cast<const float4*>(
        times + bbase + (size_t)(T - 1) * D + d0);
    const float tfirst[4] = {tf4.x, tf4.y, tf4.z, tf4.w};
    const float tlastT[4] = {tl4.x, tl4.y, tl4.z, tl4.w};
#pragma unroll
    for (int j = 0; j < 4; ++j) {
        if (fi[j] < 0) { fx[j] = 0.f; ft[j] = tfirst[j]; }
        if (bi[j] < 0) { bx[j] = 0.f; bt[j] = tlastT[j]; }
    }

    // ---- phase 5: forward fill, reverse fill + interpolate, wide store ----
    float res[4][4];
#pragma unroll
    for (int j = 0; j < 4; ++j) {
        float xl[4], tl[4];
        float cfx = fx[j], cft = ft[j];
#pragma unroll
        for (int i = 0; i < 4; ++i) {
            if ((mb[j] >> i) & 1u) { cfx = vv[i][j]; cft = tt[i][j]; }
            xl[i] = cfx; tl[i] = cft;
        }
        float cbx = bx[j], cbt = bt[j];
#pragma unroll
        for (int i = 3; i >= 0; --i) {
            const bool obs = (mb[j] >> i) & 1u;
            if (obs) { cbx = vv[i][j]; cbt = tt[i][j]; }
            const float denom = cbt - tl[i];
            const float num   = xl[i] * (cbt - tt[i][j]) + cbx * (tt[i][j] - tl[i]);
            const bool  safe  = (denom != 0.f);
            float xi = num / (safe ? denom : 1.f);
            xi = (safe && isfinite(xi)) ? xi : 0.f;
            res[i][j] = obs ? vv[i][j] : xi;
        }
    }

    float* orow = out + bbase + (size_t)t0 * D + d0;
#pragma unroll
    for (int i = 0; i < 4; ++i) {
        float4 o; o.x = res[i][0]; o.y = res[i][1]; o.z = res[i][2]; o.w = res[i][3];
        *reinterpret_cast<float4*>(orow + i * D) = o;
    }
}

extern "C" void kernel_launch(void* const* d_in, const int* in_sizes, int n_in,
                              void* d_out, int out_size, void* d_ws, size_t ws_size,
                              hipStream_t stream)
{
    const float* values = (const float*)d_in[0];
    const float* times  = (const float*)d_in[1];
    const int*   mask   = (const int*)d_in[2];
    float*       out    = (float*)d_out;

    const int total_threads = B * (T / 4) * (D / 4);   // 524288
    interp_wide_kernel<<<total_threads / 256, 256, 0, stream>>>(values, times, mask, out);
}

// Round 3
// 147.819 us; speedup vs baseline: 1.0914x; 1.0914x over previous
//
#include <hip/hip_runtime.h>
#include <math.h>

// Problem constants (fixed by reference): B=32, T=2048, D=128
constexpr int B    = 32;
constexpr int T    = 2048;
constexpr int D    = 128;
constexpr int TG   = 32;      // timesteps owned per block
constexpr int HALO = 16;      // halo steps each side
constexpr int WIN  = 64;      // HALO + TG + HALO
constexpr int APAD = 17;      // padded row bytes for nibble table (bank-conflict-free byte writes)

// Block = 256 threads = one b, one group of 32 timesteps, all 128 d.
//   thread: d4 = tid&31 (4 consecutive d), c_loc = tid>>5 (chunk of 4 timesteps).
// The block cooperatively bit-packs the mask over a 64-step window
// [t_blk-16, t_blk+48) into a per-d u64 in LDS. Every element of
// values/times/mask is read exactly once from global (mask halo: +50%),
// all as 16B-wide coalesced loads. Carry (value,time) fetches are one
// batched, branch-free scalar-gather round; fi/bi<0 redirects to row 0 /
// row T-1, which reproduces the reference init (x=0, t=times[0]/times[T-1]).
__global__ __launch_bounds__(256)
void interp_lds_kernel(const float* __restrict__ values,
                       const float* __restrict__ times,
                       const int*   __restrict__ mask,
                       float*       __restrict__ out)
{
    __shared__ unsigned char A[D * APAD];   // nibble (4 steps) per (d, step-quad)
    __shared__ unsigned      W[2][D];       // folded 64-bit window per d (lo, hi)

    const int tid   = threadIdx.x;
    const int blk   = blockIdx.x;
    const int b     = blk >> 6;             // 64 t-groups per b
    const int tg    = blk & 63;
    const int t_blk = tg * TG;
    const int w0    = t_blk - HALO;         // window start (may be negative)

    const size_t bbase = (size_t)b * T * D;

    const int d4    = tid & 31;
    const int c_loc = tid >> 5;             // 0..7
    const int d0    = d4 << 2;
    const int t0    = t_blk + (c_loc << 2);

    // ---- phase 0: own v/t tile, independent wide loads (overlap LDS build) ----
    float vv[4][4], tt[4][4];               // [timestep][chain]
    const float* vrow = values + bbase + (size_t)t0 * D + d0;
    const float* trow = times  + bbase + (size_t)t0 * D + d0;
#pragma unroll
    for (int i = 0; i < 4; ++i) {
        const float4 a = *reinterpret_cast<const float4*>(vrow + i * D);
        const float4 s = *reinterpret_cast<const float4*>(trow + i * D);
        vv[i][0] = a.x; vv[i][1] = a.y; vv[i][2] = a.z; vv[i][3] = a.w;
        tt[i][0] = s.x; tt[i][1] = s.y; tt[i][2] = s.z; tt[i][3] = s.w;
    }

    // ---- phase 1: build nibble table (each mask element read once, int4) ----
#pragma unroll
    for (int k = 0; k < 2; ++k) {
        const int task = tid + k * 256;     // 512 (step-quad, d4) tasks
        const int td4  = task & 31;
        const int ts4  = task >> 5;         // 0..15
        const int tdd  = td4 << 2;
        unsigned n0 = 0, n1 = 0, n2 = 0, n3 = 0;
#pragma unroll
        for (int i = 0; i < 4; ++i) {
            const int st = w0 + (ts4 << 2) + i;
            if (st >= 0 && st < T) {        // wave-uniform predicate
                const int4 m = *reinterpret_cast<const int4*>(
                    mask + bbase + (size_t)st * D + tdd);
                n0 |= (m.x != 0 ? 1u : 0u) << i;
                n1 |= (m.y != 0 ? 1u : 0u) << i;
                n2 |= (m.z != 0 ? 1u : 0u) << i;
                n3 |= (m.w != 0 ? 1u : 0u) << i;
            }
        }
        A[(tdd + 0) * APAD + ts4] = (unsigned char)n0;
        A[(tdd + 1) * APAD + ts4] = (unsigned char)n1;
        A[(tdd + 2) * APAD + ts4] = (unsigned char)n2;
        A[(tdd + 3) * APAD + ts4] = (unsigned char)n3;
    }
    __syncthreads();

    // ---- phase 2: fold nibbles into u32 window halves ----
    {
        const int r = tid & 127;            // d row
        const int h = tid >> 7;             // half (0 = bits 0..31, 1 = 32..63)
        unsigned acc = 0;
#pragma unroll
        for (int q = 0; q < 8; ++q)
            acc |= (unsigned)(A[r * APAD + (h << 3) + q] & 0xF) << (q << 2);
        W[h][r] = acc;
    }
    __syncthreads();

    // ---- phase 3: carry indices from register bit-scan ----
    const int pos = HALO + (c_loc << 2);    // own bits at pos..pos+3
    int fi[4], bi[4];
    unsigned mb[4];
#pragma unroll
    for (int j = 0; j < 4; ++j) {
        const unsigned long long w =
            ((unsigned long long)W[1][d0 + j] << 32) | (unsigned long long)W[0][d0 + j];
        mb[j] = (unsigned)((w >> pos) & 0xFull);
        const unsigned long long below = w & ((1ull << pos) - 1ull);   // steps < t0
        const unsigned long long above = w >> (pos + 4);               // steps > t0+3
        fi[j] = below ? (w0 + 63 - __builtin_clzll(below)) : -1;
        bi[j] = above ? (t0 + 4 + __builtin_ctzll(above)) : -1;
        // rare fallbacks (whole 16-step halo unobserved AND array edge not reached)
        if (fi[j] < 0 && w0 > 0) {
            for (int st = w0 - 1; st >= 0; --st)
                if (mask[bbase + (size_t)st * D + d0 + j] != 0) { fi[j] = st; break; }
        }
        if (bi[j] < 0 && w0 + WIN < T) {
            for (int st = w0 + WIN; st < T; ++st)
                if (mask[bbase + (size_t)st * D + d0 + j] != 0) { bi[j] = st; break; }
        }
    }

    // ---- phase 4: batched branch-free carry gathers ----
    // fi<0 -> read row 0   (times[b,0,d]   = reference forward-init t)
    // bi<0 -> read row T-1 (times[b,T-1,d] = reference backward-init t)
    float fx[4], ft[4], bx[4], bt[4];
#pragma unroll
    for (int j = 0; j < 4; ++j) {
        const int sF = (fi[j] >= 0) ? fi[j] : 0;
        const int sB = (bi[j] >= 0) ? bi[j] : (T - 1);
        const size_t oF = bbase + (size_t)sF * D + d0 + j;
        const size_t oB = bbase + (size_t)sB * D + d0 + j;
        const float lvF = values[oF], ltF = times[oF];
        const float lvB = values[oB], ltB = times[oB];
        fx[j] = (fi[j] >= 0) ? lvF : 0.f;
        ft[j] = ltF;
        bx[j] = (bi[j] >= 0) ? lvB : 0.f;
        bt[j] = ltB;
    }

    // ---- phase 5: forward fill, reverse fill + interpolate, wide store ----
    float res[4][4];
#pragma unroll
    for (int j = 0; j < 4; ++j) {
        float xl[4], tl[4];
        float cfx = fx[j], cft = ft[j];
#pragma unroll
        for (int i = 0; i < 4; ++i) {
            if ((mb[j] >> i) & 1u) { cfx = vv[i][j]; cft = tt[i][j]; }
            xl[i] = cfx; tl[i] = cft;
        }
        float cbx = bx[j], cbt = bt[j];
#pragma unroll
        for (int i = 3; i >= 0; --i) {
            const bool obs = (mb[j] >> i) & 1u;
            if (obs) { cbx = vv[i][j]; cbt = tt[i][j]; }
            const float denom = cbt - tl[i];
            const float num   = xl[i] * (cbt - tt[i][j]) + cbx * (tt[i][j] - tl[i]);
            const bool  safe  = (denom != 0.f);
            float xi = num / (safe ? denom : 1.f);
            xi = (safe && isfinite(xi)) ? xi : 0.f;
            res[i][j] = obs ? vv[i][j] : xi;
        }
    }

    float* orow = out + bbase + (size_t)t0 * D + d0;
#pragma unroll
    for (int i = 0; i < 4; ++i) {
        float4 o; o.x = res[i][0]; o.y = res[i][1]; o.z = res[i][2]; o.w = res[i][3];
        *reinterpret_cast<float4*>(orow + i * D) = o;
    }
}

extern "C" void kernel_launch(void* const* d_in, const int* in_sizes, int n_in,
                              void* d_out, int out_size, void* d_ws, size_t ws_size,
                              hipStream_t stream)
{
    const float* values = (const float*)d_in[0];
    const float* times  = (const float*)d_in[1];
    const int*   mask   = (const int*)d_in[2];
    float*       out    = (float*)d_out;

    const int blocks = B * (T / TG);        // 32 * 64 = 2048 blocks of 256
    interp_lds_kernel<<<blocks, 256, 0, stream>>>(values, times, mask, out);
}

// Round 4
// 145.052 us; speedup vs baseline: 1.1123x; 1.0191x over previous
//
#include <hip/hip_runtime.h>
#include <math.h>

// Problem constants (fixed by reference): B=32, T=2048, D=128
constexpr int B   = 32;
constexpr int T   = 2048;
constexpr int D   = 128;
constexpr int CS  = 8;           // timesteps per thread
constexpr int RT  = 8;           // thread-rows per block
constexpr int BT  = RT * CS;     // 64 timesteps per block
constexpr int PAD = 129;         // LDS row pad (floats) -> <=4-way bank aliasing

// Block = 256 threads = (b, 64 consecutive timesteps, all 128 d).
//   thread: d4 = tid&31 (4 consecutive d), row = tid>>5 (8 timesteps).
// All bulk traffic (values/times/mask/out) is float4/int4, each element
// touched exactly once. Carry resolution: each thread publishes per-chain
// {last-obs (v,t), first-obs (v,t), mask} -- computed from its own
// registers -- to a 20KB LDS table; ONE barrier; interior threads resolve
// both carries entirely from LDS (zero global transactions). Only rows 0/7
// probe a 16-step halo (coalesced int4), and the P~2^-8 all-empty-rows
// case falls back to a serial global scan (exact reference semantics).
__global__ __launch_bounds__(256)
void interp_xchg_kernel(const float* __restrict__ values,
                        const float* __restrict__ times,
                        const int*   __restrict__ mask,
                        float*       __restrict__ out)
{
    __shared__ float    SLV[RT][PAD];   // last observed value in row
    __shared__ float    SLT[RT][PAD];   // last observed time in row
    __shared__ float    SFV[RT][PAD];   // first observed value in row
    __shared__ float    SFT[RT][PAD];   // first observed time in row
    __shared__ unsigned SM [RT][PAD];   // 8-bit observation mask of row

    const int tid = threadIdx.x;
    const int d4  = tid & 31;
    const int row = tid >> 5;
    const int d0  = d4 << 2;

    const int blk = blockIdx.x;
    const int b   = blk >> 5;            // 32 t-blocks per b
    const int tb  = blk & 31;
    const int bt0 = tb * BT;
    const int t0  = bt0 + row * CS;

    const size_t bbase = (size_t)b * T * D;
    const float* vrow = values + bbase + (size_t)t0 * D + d0;
    const float* trow = times  + bbase + (size_t)t0 * D + d0;
    const int*   mrow = mask   + bbase + (size_t)t0 * D + d0;

    // ---- own tile: 24 independent wide loads ----
    float vv[CS][4], tt[CS][4];
    unsigned mb[4] = {0u, 0u, 0u, 0u};
#pragma unroll
    for (int i = 0; i < CS; ++i) {
        const float4 a = *reinterpret_cast<const float4*>(vrow + i * D);
        const float4 s = *reinterpret_cast<const float4*>(trow + i * D);
        const int4   m = *reinterpret_cast<const int4*>(mrow + i * D);
        vv[i][0] = a.x; vv[i][1] = a.y; vv[i][2] = a.z; vv[i][3] = a.w;
        tt[i][0] = s.x; tt[i][1] = s.y; tt[i][2] = s.z; tt[i][3] = s.w;
        mb[0] |= (m.x != 0 ? 1u : 0u) << i;
        mb[1] |= (m.y != 0 ? 1u : 0u) << i;
        mb[2] |= (m.z != 0 ? 1u : 0u) << i;
        mb[3] |= (m.w != 0 ? 1u : 0u) << i;
    }

    // ---- block-edge halo probes (coalesced int4, issued before barrier) ----
    unsigned pb[4] = {0u, 0u, 0u, 0u};   // 16 steps before block (row 0 only)
    unsigned nb[4] = {0u, 0u, 0u, 0u};   // 16 steps after block (row RT-1 only)
    if (row == 0 && bt0 > 0) {
#pragma unroll
        for (int k = 0; k < 16; ++k) {
            const int st = bt0 - 16 + k;
            const int4 m = *reinterpret_cast<const int4*>(
                mask + bbase + (size_t)st * D + d0);
            pb[0] |= (m.x != 0 ? 1u : 0u) << k;
            pb[1] |= (m.y != 0 ? 1u : 0u) << k;
            pb[2] |= (m.z != 0 ? 1u : 0u) << k;
            pb[3] |= (m.w != 0 ? 1u : 0u) << k;
        }
    }
    if (row == RT - 1 && bt0 + BT < T) {
#pragma unroll
        for (int k = 0; k < 16; ++k) {
            const int st = bt0 + BT + k;
            const int4 m = *reinterpret_cast<const int4*>(
                mask + bbase + (size_t)st * D + d0);
            nb[0] |= (m.x != 0 ? 1u : 0u) << k;
            nb[1] |= (m.y != 0 ? 1u : 0u) << k;
            nb[2] |= (m.z != 0 ? 1u : 0u) << k;
            nb[3] |= (m.w != 0 ? 1u : 0u) << k;
        }
    }

    // ---- publish per-chain summaries (from registers, unrolled selects) ----
#pragma unroll
    for (int j = 0; j < 4; ++j) {
        float lv = 0.f, lt = 0.f, fv = 0.f, ft = 0.f;
#pragma unroll
        for (int i = 0; i < CS; ++i)
            if ((mb[j] >> i) & 1u) { lv = vv[i][j]; lt = tt[i][j]; }
#pragma unroll
        for (int i = CS - 1; i >= 0; --i)
            if ((mb[j] >> i) & 1u) { fv = vv[i][j]; ft = tt[i][j]; }
        const int d = d0 + j;
        SLV[row][d] = lv; SLT[row][d] = lt;
        SFV[row][d] = fv; SFT[row][d] = ft;
        SM [row][d] = mb[j];
    }
    __syncthreads();

    // ---- resolve carries + fill + interpolate, per chain ----
    float res[CS][4];
#pragma unroll
    for (int j = 0; j < 4; ++j) {
        const int d = d0 + j;

        // forward carry: nearest observation strictly before t0
        float cfx = 0.f, cft = 0.f;
        bool have = false;
        for (int r = row - 1; r >= 0; --r) {
            if (SM[r][d]) { cfx = SLV[r][d]; cft = SLT[r][d]; have = true; break; }
        }
        if (!have && pb[j]) {                       // row-0 halo hit
            const int st = bt0 - 16 + (31 - __builtin_clz(pb[j]));
            const size_t o = bbase + (size_t)st * D + d;
            cfx = values[o]; cft = times[o]; have = true;
        }
        if (!have) {                                // rare serial fallback
            const int start = (row == 0) ? (bt0 - 17) : (bt0 - 1);
            for (int st = start; st >= 0; --st) {
                if (mask[bbase + (size_t)st * D + d] != 0) {
                    const size_t o = bbase + (size_t)st * D + d;
                    cfx = values[o]; cft = times[o]; have = true; break;
                }
            }
        }
        if (!have) { cfx = 0.f; cft = times[bbase + d]; }      // reference init

        // backward carry: nearest observation strictly after t0+CS-1
        float cbx = 0.f, cbt = 0.f;
        bool haveb = false;
        for (int r = row + 1; r < RT; ++r) {
            if (SM[r][d]) { cbx = SFV[r][d]; cbt = SFT[r][d]; haveb = true; break; }
        }
        if (!haveb && nb[j]) {                      // row-7 halo hit
            const int st = bt0 + BT + __builtin_ctz(nb[j]);
            const size_t o = bbase + (size_t)st * D + d;
            cbx = values[o]; cbt = times[o]; haveb = true;
        }
        if (!haveb) {                               // rare serial fallback
            const int start = bt0 + BT + ((row == RT - 1) ? 16 : 0);
            for (int st = start; st < T; ++st) {
                if (mask[bbase + (size_t)st * D + d] != 0) {
                    const size_t o = bbase + (size_t)st * D + d;
                    cbx = values[o]; cbt = times[o]; haveb = true; break;
                }
            }
        }
        if (!haveb) { cbx = 0.f; cbt = times[bbase + (size_t)(T - 1) * D + d]; }

        // forward fill (includes current step, like reference cummax)
        float xl[CS], tl_[CS];
#pragma unroll
        for (int i = 0; i < CS; ++i) {
            if ((mb[j] >> i) & 1u) { cfx = vv[i][j]; cft = tt[i][j]; }
            xl[i] = cfx; tl_[i] = cft;
        }
        // reverse fill + interpolate (math identical to verified kernels)
#pragma unroll
        for (int i = CS - 1; i >= 0; --i) {
            const bool obs = (mb[j] >> i) & 1u;
            if (obs) { cbx = vv[i][j]; cbt = tt[i][j]; }
            const float denom = cbt - tl_[i];
            const float num   = xl[i] * (cbt - tt[i][j]) + cbx * (tt[i][j] - tl_[i]);
            const bool  safe  = (denom != 0.f);
            float xi = num / (safe ? denom : 1.f);
            xi = (safe && isfinite(xi)) ? xi : 0.f;
            res[i][j] = obs ? vv[i][j] : xi;
        }
    }

    // ---- wide stores ----
    float* orow = out + bbase + (size_t)t0 * D + d0;
#pragma unroll
    for (int i = 0; i < CS; ++i) {
        float4 o; o.x = res[i][0]; o.y = res[i][1]; o.z = res[i][2]; o.w = res[i][3];
        *reinterpret_cast<float4*>(orow + i * D) = o;
    }
}

extern "C" void kernel_launch(void* const* d_in, const int* in_sizes, int n_in,
                              void* d_out, int out_size, void* d_ws, size_t ws_size,
                              hipStream_t stream)
{
    const float* values = (const float*)d_in[0];
    const float* times  = (const float*)d_in[1];
    const int*   mask   = (const int*)d_in[2];
    float*       out    = (float*)d_out;

    const int blocks = B * (T / BT);     // 32 * 32 = 1024 blocks of 256
    interp_xchg_kernel<<<blocks, 256, 0, stream>>>(values, times, mask, out);
}